// Round 5
// baseline (41.398 us; speedup 1.0000x reference)
//
#include <hip/hip_runtime.h>
#include <hip/hip_bf16.h>

#define NEGC (-1e8f)
#define NBLK 128
#define NTHR 512
#define BI 8

__device__ __forceinline__ float lrelu(float x) { return x >= 0.f ? x : 0.2f * x; }

// Shared edge-logit computation. MUST be bit-identical between the stats phase
// and the output phase: the neg-mask multiplies e by -1e8, so a 1-ulp
// difference becomes ~±50 in the logit and exp() explodes. Add/mul only (no
// fma-contraction ambiguity), fixed association e = ss + soj.
__device__ __forceinline__ void edge_pq(float ss, float soj, bool same,
                                        float& p, float& q) {
    float e = ss + soj;
    float pin = same ? e : e * NEGC;
    float nin = same ? e * NEGC : e;
    p = lrelu(pin);
    q = lrelu(nin);
}

// Device-scope grid barrier. Safe: grid=128 blocks of 512 thr / 32 KB LDS ->
// per-CU capacity >= 4 blocks, so all 128 blocks are resident regardless of
// placement. Counters zeroed via hipMemsetAsync at every launch.
__device__ __forceinline__ void grid_barrier(unsigned* ctr) {
    __syncthreads();
    if (threadIdx.x == 0) {
        __threadfence();  // agent release: writes (incl. L2) visible device-wide
        __hip_atomic_fetch_add(ctr, 1u, __ATOMIC_ACQ_REL, __HIP_MEMORY_SCOPE_AGENT);
        while (__hip_atomic_load(ctr, __ATOMIC_RELAXED, __HIP_MEMORY_SCOPE_AGENT)
               < (unsigned)NBLK) {
            __builtin_amdgcn_s_sleep(2);
        }
        __threadfence();  // agent acquire: invalidate stale L1/L2 lines
    }
    __syncthreads();
}

__global__ __launch_bounds__(NTHR) void fused_kernel(
        const float* __restrict__ node, const int* __restrict__ group,
        const float* __restrict__ W_emb, const float* __restrict__ b_emb,
        const float* __restrict__ w_att, const float* __restrict__ b_att,
        float* __restrict__ s_other_g, float* __restrict__ s_self_g,
        float* __restrict__ cmp_g, float* __restrict__ icsp_g,
        float* __restrict__ cmn_g, float* __restrict__ icsn_g,
        unsigned* __restrict__ bar, float* __restrict__ out) {
    int t = threadIdx.x;
    int b = blockIdx.x;
    int wv = t >> 6, lane = t & 63;
    float ba = b_att[0];

    __shared__ float lds[8192];   // 32 KB, multi-use

    // ---------------- Phase 1: u1/u2/c (redundant per block, tiny) + row scores
    {
        int k = t & 127, q = t >> 7;           // quarter q of the e-range
        float p1 = 0.f, p2 = 0.f;
        for (int e = 32 * q; e < 32 * q + 32; ++e) {
            float w = W_emb[e * 128 + k];
            p1 += w * w_att[e];
            p2 += w * w_att[128 + e];
        }
        lds[q * 256 + k] = p1;
        lds[q * 256 + 128 + k] = p2;
        __syncthreads();
        if (t < 128) {
            lds[1024 + t] = lds[t] + lds[256 + t] + lds[512 + t] + lds[768 + t];
        } else if (t < 256) {
            int kk = t - 128;
            lds[1152 + kk] = lds[128 + kk] + lds[384 + kk] + lds[640 + kk] + lds[896 + kk];
        } else if (t < 320) {        // wave 4: c1 = dot(b_emb, w_att[:128])
            int l = t - 256;
            float cc = b_emb[l] * w_att[l] + b_emb[64 + l] * w_att[64 + l];
            for (int off = 32; off > 0; off >>= 1) cc += __shfl_xor(cc, off, 64);
            if (l == 0) lds[1280] = cc;
        } else if (t < 384) {        // wave 5: c2 = dot(b_emb, w_att[128:])
            int l = t - 320;
            float cc = b_emb[l] * w_att[128 + l] + b_emb[64 + l] * w_att[192 + l];
            for (int off = 32; off > 0; off >>= 1) cc += __shfl_xor(cc, off, 64);
            if (l == 0) lds[1281] = cc;
        }
        __syncthreads();
        // row dots: wave wv handles row b*8 + wv
        int i = b * BI + wv;
        const float2* row2 = (const float2*)(node + (size_t)i * 128);
        const float2* u12 = (const float2*)&lds[1024];
        const float2* u22 = (const float2*)&lds[1152];
        float2 x = row2[lane];
        float2 ua = u12[lane];
        float2 ub = u22[lane];
        float d1 = x.x * ua.x + x.y * ua.y;
        float d2 = x.x * ub.x + x.y * ub.y;
        for (int off = 32; off > 0; off >>= 1) {
            d1 += __shfl_xor(d1, off, 64);
            d2 += __shfl_xor(d2, off, 64);
        }
        if (lane == 0) {
            s_other_g[i] = d1 + lds[1280];
            s_self_g[i]  = d2 + lds[1281];
        }
    }
    grid_barrier(bar + 0);

    // ---------------- Phase 2: per-column softmax stats; wave wv -> col b*8+wv
    {
        int j = b * BI + wv;
        float soj = s_other_g[j] + ba;        // the one fixed association
        int gj = group[j];
        float pv[16], nv[16];
        float pmax = -3.4e38f, nmax = -3.4e38f;
#pragma unroll
        for (int k = 0; k < 16; ++k) {
            int i = lane + k * 64;
            float p, q;
            edge_pq(s_self_g[i], soj, group[i] == gj, p, q);
            pv[k] = p; nv[k] = q;
            pmax = fmaxf(pmax, p);
            nmax = fmaxf(nmax, q);
        }
#pragma unroll
        for (int off = 32; off > 0; off >>= 1) {
            pmax = fmaxf(pmax, __shfl_xor(pmax, off, 64));
            nmax = fmaxf(nmax, __shfl_xor(nmax, off, 64));
        }
        float ps = 0.f, ns = 0.f;
#pragma unroll
        for (int k = 0; k < 16; ++k) {
            ps += __expf(pv[k] - pmax);
            ns += __expf(nv[k] - nmax);
        }
#pragma unroll
        for (int off = 32; off > 0; off >>= 1) {
            ps += __shfl_xor(ps, off, 64);
            ns += __shfl_xor(ns, off, 64);
        }
        if (lane == 0) {
            cmp_g[j] = pmax; icsp_g[j] = 1.f / ps;
            cmn_g[j] = nmax; icsn_g[j] = 1.f / ns;
        }
    }
    grid_barrier(bar + 1);

    // ---------------- Phase 3: out[i,:] = sum_j A[i,j] * relu(node[j,:])
    {
        int i0 = b * BI;
        float ss[BI]; int gl[BI];
#pragma unroll
        for (int r = 0; r < BI; ++r) { ss[r] = s_self_g[i0 + r]; gl[r] = group[i0 + r]; }

        // fill bufT[j][r] = lds[j*8 + r]; each thread handles 2 j's, all 8 r's
#pragma unroll
        for (int e = 0; e < 2; ++e) {
            int j = t + e * 512;
            float soj = s_other_g[j] + ba;    // identical association to phase 2
            int gj = group[j];
            float mp = cmp_g[j], ip = icsp_g[j], mn = cmn_g[j], iq = icsn_g[j];
            float tmp[8];
#pragma unroll
            for (int r = 0; r < BI; ++r) {
                float p, q;
                edge_pq(ss[r], soj, gj == gl[r], p, q);
                tmp[r] = __expf(p - mp) * ip + __expf(q - mn) * iq;
            }
            *(float4*)&lds[j * 8]     = make_float4(tmp[0], tmp[1], tmp[2], tmp[3]);
            *(float4*)&lds[j * 8 + 4] = make_float4(tmp[4], tmp[5], tmp[6], tmp[7]);
        }
        __syncthreads();

        int g = t >> 5, l32 = t & 31;         // 16 j-groups of 32 lanes
        const float4* nf4 = (const float4*)node;
        float4 acc[BI];
#pragma unroll
        for (int r = 0; r < BI; ++r) acc[r] = make_float4(0.f, 0.f, 0.f, 0.f);

#pragma unroll 8
        for (int j = g; j < 1024; j += 16) {
            float4 a0 = *(const float4*)&lds[j * 8];       // broadcast reads
            float4 a1 = *(const float4*)&lds[j * 8 + 4];
            float4 x = nf4[(size_t)j * 32 + l32];          // coalesced
            float4 rn = make_float4(fmaxf(x.x, 0.f), fmaxf(x.y, 0.f),
                                    fmaxf(x.z, 0.f), fmaxf(x.w, 0.f));
            float aa[8] = {a0.x, a0.y, a0.z, a0.w, a1.x, a1.y, a1.z, a1.w};
#pragma unroll
            for (int r = 0; r < BI; ++r) {
                acc[r].x += aa[r] * rn.x; acc[r].y += aa[r] * rn.y;
                acc[r].z += aa[r] * rn.z; acc[r].w += aa[r] * rn.w;
            }
        }

        // fold the two 32-lane groups of each wave in-register
#pragma unroll
        for (int r = 0; r < BI; ++r) {
            acc[r].x += __shfl_xor(acc[r].x, 32, 64);
            acc[r].y += __shfl_xor(acc[r].y, 32, 64);
            acc[r].z += __shfl_xor(acc[r].z, 32, 64);
            acc[r].w += __shfl_xor(acc[r].w, 32, 64);
        }

        __syncthreads();  // done reading bufT; reuse lds[0..8191] as reduce buffer
        if ((t & 32) == 0) {
            int hg = g >> 1;                   // 0..7
            float4* redf4 = (float4*)&lds[0];  // redf4[hg*256 + r*32 + l32]
#pragma unroll
            for (int r = 0; r < BI; ++r) redf4[hg * (BI * 32) + r * 32 + l32] = acc[r];
        }
        __syncthreads();

        // 1024 outputs (8 rows x 128 d); 2 per thread
#pragma unroll
        for (int s = 0; s < 2; ++s) {
            int o = t + s * 512;
            int r = o >> 7, d = o & 127;
            float sum = 0.f;
#pragma unroll
            for (int hg = 0; hg < 8; ++hg) sum += lds[hg * 1024 + r * 128 + d];
            out[(size_t)(i0 + r) * 128 + d] = sum;
        }
    }
}

extern "C" void kernel_launch(void* const* d_in, const int* in_sizes, int n_in,
                              void* d_out, int out_size, void* d_ws, size_t ws_size,
                              hipStream_t stream) {
    const float* node  = (const float*)d_in[0];
    const int*   group = (const int*)d_in[1];
    const float* W_emb = (const float*)d_in[2];
    const float* b_emb = (const float*)d_in[3];
    const float* w_att = (const float*)d_in[4];
    const float* b_att = (const float*)d_in[5];
    float* out = (float*)d_out;

    float* w = (float*)d_ws;
    float* s_other = w;             // 1024
    float* s_self  = w + 1024;
    float* cmp     = w + 2048;
    float* icsp    = w + 3072;
    float* cmn     = w + 4096;
    float* icsn    = w + 5120;
    unsigned* bar  = (unsigned*)((char*)d_ws + 32768);  // 2 counters

    hipMemsetAsync(bar, 0, 8, stream);  // zero barrier counters every launch
    fused_kernel<<<NBLK, NTHR, 0, stream>>>(node, group, W_emb, b_emb, w_att,
                                            b_att, s_other, s_self, cmp, icsp,
                                            cmn, icsn, bar, out);
}

// Round 6
// 34.924 us; speedup vs baseline: 1.1854x; 1.1854x over previous
//
#include <hip/hip_runtime.h>
#include <hip/hip_bf16.h>

#define NEGC (-1e8f)

__device__ __forceinline__ float lrelu(float x) { return x >= 0.f ? x : 0.2f * x; }

// Shared edge-logit computation. MUST be bit-identical between the stats pass
// and the output pass: the neg-mask multiplies e by -1e8, so a 1-ulp
// difference becomes ~±50 in the logit and exp() explodes. Add/mul only (no
// fma-contraction ambiguity), fixed association e = ss + soj, with
// soj = s_other[j] + b_att computed identically in both kernels from the
// SAME stored s_other bits.
__device__ __forceinline__ void edge_pq(float ss, float soj, bool same,
                                        float& p, float& q) {
    float e = ss + soj;
    float pin = same ? e : e * NEGC;
    float nin = same ? e * NEGC : e;
    p = lrelu(pin);
    q = lrelu(nin);
}

// ---------------- Kernel A: 128 blocks x 512 thr. Block b owns rows/cols
// [8b, 8b+8). Redundantly computes u1/u2/c1/c2 and ALL s_self (into LDS) —
// deterministic, so every block produces bit-identical values — then column
// softmax stats for its 8 columns. Writes its s_self/s_other slice + stats.
__global__ __launch_bounds__(512) void kA_scores_stats(
        const float* __restrict__ node, const int* __restrict__ group,
        const float* __restrict__ W_emb, const float* __restrict__ b_emb,
        const float* __restrict__ w_att, const float* __restrict__ b_att,
        float* __restrict__ s_other_g, float* __restrict__ s_self_g,
        float* __restrict__ cmp_g, float* __restrict__ icsp_g,
        float* __restrict__ cmn_g, float* __restrict__ icsn_g) {
    int t = threadIdx.x;
    int b = blockIdx.x;
    int wv = t >> 6, lane = t & 63;

    __shared__ float part[1024];
    __shared__ float u1[128], u2[128];
    __shared__ float sself[1024];
    __shared__ int   grp[1024];
    __shared__ float cc[2];
    __shared__ float sothr[8];

    // --- u1/u2 partials: quarter q of the e-range, column k
    {
        int k = t & 127, q = t >> 7;
        float p1 = 0.f, p2 = 0.f;
        for (int e = 32 * q; e < 32 * q + 32; ++e) {
            float w = W_emb[e * 128 + k];
            p1 += w * w_att[e];
            p2 += w * w_att[128 + e];
        }
        part[q * 256 + k] = p1;
        part[q * 256 + 128 + k] = p2;
    }
    __syncthreads();
    if (t < 128) {
        u1[t] = part[t] + part[256 + t] + part[512 + t] + part[768 + t];
    } else if (t < 256) {
        int k = t - 128;
        u2[k] = part[128 + k] + part[384 + k] + part[640 + k] + part[896 + k];
    } else if (t < 320) {              // c1 = dot(b_emb, w_att[:128])
        int l = t - 256;
        float c = b_emb[l] * w_att[l] + b_emb[64 + l] * w_att[64 + l];
        for (int off = 32; off > 0; off >>= 1) c += __shfl_xor(c, off, 64);
        if (l == 0) cc[0] = c;
    } else if (t < 384) {              // c2 = dot(b_emb, w_att[128:])
        int l = t - 320;
        float c = b_emb[l] * w_att[128 + l] + b_emb[64 + l] * w_att[192 + l];
        for (int off = 32; off > 0; off >>= 1) c += __shfl_xor(c, off, 64);
        if (l == 0) cc[1] = c;
    }
    __syncthreads();

    // --- s_self for ALL rows (2 per thread), group to LDS
    const float4* u24 = (const float4*)u2;
#pragma unroll
    for (int e = 0; e < 2; ++e) {
        int i = t + e * 512;
        const float4* row4 = (const float4*)(node + (size_t)i * 128);
        float a = 0.f;
#pragma unroll 8
        for (int k = 0; k < 32; ++k) {
            float4 x = row4[k];
            float4 v = u24[k];
            a += x.x * v.x + x.y * v.y + x.z * v.z + x.w * v.w;
        }
        sself[i] = a + cc[1];
        grp[i] = group[i];
    }

    // --- s_other for the block's 8 columns: wave wv -> col 8b+wv
    {
        int j = b * 8 + wv;
        const float2* row2 = (const float2*)(node + (size_t)j * 128);
        const float2* u12 = (const float2*)u1;
        float2 x = row2[lane], v = u12[lane];
        float d = x.x * v.x + x.y * v.y;
        for (int off = 32; off > 0; off >>= 1) d += __shfl_xor(d, off, 64);
        if (lane == 0) {
            float so = d + cc[0];
            sothr[wv] = so;
            s_other_g[j] = so;       // same bits K_B will load
        }
    }
    __syncthreads();

    if (t < 8) s_self_g[b * 8 + t] = sself[b * 8 + t];  // block's row slice

    // --- column stats: wave wv -> col j = 8b+wv
    float ba = b_att[0];
    float soj = sothr[wv] + ba;      // identical association to K_B
    int gj = grp[b * 8 + wv];
    float pv[16], nv[16];
    float pmax = -3.4e38f, nmax = -3.4e38f;
#pragma unroll
    for (int k = 0; k < 16; ++k) {
        int i = lane + k * 64;
        float p, q;
        edge_pq(sself[i], soj, grp[i] == gj, p, q);
        pv[k] = p; nv[k] = q;
        pmax = fmaxf(pmax, p);
        nmax = fmaxf(nmax, q);
    }
#pragma unroll
    for (int off = 32; off > 0; off >>= 1) {
        pmax = fmaxf(pmax, __shfl_xor(pmax, off, 64));
        nmax = fmaxf(nmax, __shfl_xor(nmax, off, 64));
    }
    float ps = 0.f, ns = 0.f;
#pragma unroll
    for (int k = 0; k < 16; ++k) {
        ps += __expf(pv[k] - pmax);
        ns += __expf(nv[k] - nmax);
    }
#pragma unroll
    for (int off = 32; off > 0; off >>= 1) {
        ps += __shfl_xor(ps, off, 64);
        ns += __shfl_xor(ns, off, 64);
    }
    if (lane == 0) {
        int j = b * 8 + wv;
        cmp_g[j] = pmax; icsp_g[j] = 1.f / ps;
        cmn_g[j] = nmax; icsn_g[j] = 1.f / ns;
    }
}

// ---------------- Kernel B: out[i,:] = sum_j A[i,j] * relu(node[j,:])
// BI=4 rows/block, 256 blocks x 512 thr. A rows filled once in 16 KB LDS;
// 16 j-groups of 32 lanes: 64-iter main loop, unroll 8. 32 KB LDS reused
// for the cross-group reduce. (Proven structure from R4.)
#define BI 4
__global__ __launch_bounds__(512) void kB_out(
        const float* __restrict__ node,
        const float* __restrict__ s_self,
        const float* __restrict__ s_other,
        const int* __restrict__ group,
        const float* __restrict__ b_att,
        const float* __restrict__ cmp, const float* __restrict__ icsp,
        const float* __restrict__ cmn, const float* __restrict__ icsn,
        float* __restrict__ out) {
    int t = threadIdx.x;       // 0..511
    int i0 = blockIdx.x * BI;

    __shared__ float buf[8192];   // 32 KB; first 4096 floats = sA[4][1024]
    __shared__ float ss_l[BI];
    __shared__ int   g_l[BI];
    if (t < BI) { ss_l[t] = s_self[i0 + t]; g_l[t] = group[i0 + t]; }
    __syncthreads();

    float ba = b_att[0];
#pragma unroll
    for (int e = 0; e < 8; ++e) {
        int idx = t + e * 512;        // 0..4095
        int r = idx >> 10;            // row 0..3
        int j = idx & 1023;
        float soj = s_other[j] + ba;  // identical association to kA
        float p, q;
        edge_pq(ss_l[r], soj, group[j] == g_l[r], p, q);
        buf[r * 1024 + j] = __expf(p - cmp[j]) * icsp[j]
                          + __expf(q - cmn[j]) * icsn[j];
    }
    __syncthreads();

    int lane = t & 31;   // float4 index within a 128-d row
    int g = t >> 5;      // j-group 0..15
    const float4* nf4 = (const float4*)node;

    float4 acc[BI];
#pragma unroll
    for (int r = 0; r < BI; ++r) acc[r] = make_float4(0.f, 0.f, 0.f, 0.f);

#pragma unroll 8
    for (int j = g; j < 1024; j += 16) {
        float4 x = nf4[(size_t)j * 32 + lane];
        float4 rn;
        rn.x = fmaxf(x.x, 0.f); rn.y = fmaxf(x.y, 0.f);
        rn.z = fmaxf(x.z, 0.f); rn.w = fmaxf(x.w, 0.f);
#pragma unroll
        for (int r = 0; r < BI; ++r) {
            float a = buf[r * 1024 + j];
            acc[r].x += a * rn.x; acc[r].y += a * rn.y;
            acc[r].z += a * rn.z; acc[r].w += a * rn.w;
        }
    }

    __syncthreads();  // done reading sA; reuse buf as reduce buffer
    float4* red = (float4*)buf;   // red[g*128 + r*32 + lane], 2048 float4
#pragma unroll
    for (int r = 0; r < BI; ++r) red[g * 128 + r * 32 + lane] = acc[r];
    __syncthreads();

    // 512 outputs (BI rows x 128 d); 1 per thread, contiguous store
    int r = t >> 7;
    int d = t & 127;
    float sum = 0.f;
#pragma unroll
    for (int gg = 0; gg < 16; ++gg)
        sum += buf[gg * 512 + r * 128 + d];
    out[(size_t)(i0 + r) * 128 + d] = sum;
}

extern "C" void kernel_launch(void* const* d_in, const int* in_sizes, int n_in,
                              void* d_out, int out_size, void* d_ws, size_t ws_size,
                              hipStream_t stream) {
    const float* node  = (const float*)d_in[0];
    const int*   group = (const int*)d_in[1];
    const float* W_emb = (const float*)d_in[2];
    const float* b_emb = (const float*)d_in[3];
    const float* w_att = (const float*)d_in[4];
    const float* b_att = (const float*)d_in[5];
    float* out = (float*)d_out;

    float* w = (float*)d_ws;
    float* s_other = w;             // 1024
    float* s_self  = w + 1024;
    float* cmp     = w + 2048;
    float* icsp    = w + 3072;
    float* cmn     = w + 4096;
    float* icsn    = w + 5120;

    kA_scores_stats<<<128, 512, 0, stream>>>(node, group, W_emb, b_emb, w_att,
                                             b_att, s_other, s_self, cmp, icsp,
                                             cmn, icsn);
    kB_out<<<256, 512, 0, stream>>>(node, s_self, s_other, group, b_att,
                                    cmp, icsp, cmn, icsn, out);
}